// Round 2
// baseline (219.802 us; speedup 1.0000x reference)
//
#include <hip/hip_runtime.h>
#include <hip/hip_bf16.h>
#include <hip/hip_cooperative_groups.h>

// PairRE scoring: out[b,n] = -|| t_hat[n]*rt[b] - h_hat[b]*rh[b] ||_2
// B=512, N=2048, E=256.
//
// x(b,n) = dot([T^2 | T]_n , [rt^2 | -2*rt*Hh]_b) + c_b,
//   T = t/||t||, Hh = (h/||h||)*rh, c_b = ||Hh_b||^2.
//
// R6 (coop fusion): R5 post-mortem showed the LDS-fused kernel was
// latency-bound on 25x-redundant per-block prep (VALUBusy 28.7%, Mfma 0.9%,
// 41us). R4's two-dispatch version dedup'd prep but paid an extra dispatch
// boundary. This round: ONE cooperative dispatch. Phase 1 = R4's prep,
// one row per wave (2048 waves, zero redundancy), fragments to workspace.
// Grid-wide sync with explicit agent-scope fences (L2 writeback+invalidate
// -> correctness does NOT depend on XCD placement). Phase 2 = R4's proven
// no-LDS score (2x2 wave grid, L1-dedup'd A/T streams, XCD-friendly block
// mapping as a perf-only heuristic).
// Fallback 1: coop launch fails -> R4 two-kernel path. Fallback 2: no
// workspace -> pure fp32 kernel.

#define B_DIM 512
#define N_DIM 2048
#define E_DIM 256
#define K_DIM 512
#define NSTEP 16        // K/32 MFMA k-steps
#define FRAG_US 512     // ushorts per packed fragment (64 lanes * 8)

namespace cg = cooperative_groups;

typedef __attribute__((ext_vector_type(8))) __bf16 bf16x8;
typedef __attribute__((ext_vector_type(4))) float f32x4;

__device__ inline ushort f2bf(float x) {
    __hip_bfloat16 h = __float2bfloat16(x);   // RNE
    union { __hip_bfloat16 b; ushort u; } cv_; cv_.b = h; return cv_.u;
}

__device__ inline float wave_sum(float v) {
#pragma unroll
    for (int m = 1; m < 64; m <<= 1) v += __shfl_xor(v, m, 64);
    return v;
}

// ---------------- prep bodies (identical numerics to R4) ----------------
// Packed addr for row r=g*16+m, k=c*8+j (c=s*4+q): dst=((g*16+s)*64+q*16+m)*8
// Lane writes k0=lane*8 .. +7  ->  s=lane>>2, q=lane&3.
__device__ __forceinline__ void prep_T_row(const float* __restrict__ tail,
        ushort* __restrict__ Tbig, int n, int lane) {
    const int s_ = lane >> 2, q = lane & 3;
    const int k0 = lane * 8;
    const bool sqr = (k0 < E_DIM);
    const int e0 = k0 & (E_DIM - 1);
    const float* row = tail + (size_t)n * E_DIM;
    const float4 v4 = ((const float4*)row)[lane];
    const float s = wave_sum(v4.x * v4.x + v4.y * v4.y + v4.z * v4.z + v4.w * v4.w);
    const float inv = 1.0f / fmaxf(sqrtf(s), 1e-12f);
    const float4 f0 = *(const float4*)(row + e0);
    const float4 f1 = *(const float4*)(row + e0 + 4);
    const float v[8] = {f0.x, f0.y, f0.z, f0.w, f1.x, f1.y, f1.z, f1.w};
    ushort u[8];
#pragma unroll
    for (int j = 0; j < 8; ++j) {
        float x = v[j] * inv;
        if (sqr) x *= x;
        u[j] = f2bf(x);
    }
    const int g = n >> 4, m = n & 15;
    *(uint4*)(Tbig + (size_t)((g * 16 + s_) * 64 + q * 16 + m) * 8) = *(const uint4*)u;
}

__device__ __forceinline__ void prep_A_row(const float* __restrict__ head,
        const float* __restrict__ rel, const int* __restrict__ rid,
        ushort* __restrict__ Abig, float* __restrict__ cvec, int b, int lane) {
    const int s_ = lane >> 2, q = lane & 3;
    const int k0 = lane * 8;
    const bool sqr = (k0 < E_DIM);
    const int e0 = k0 & (E_DIM - 1);
    const int id = rid[b];
    const float* hrow  = head + (size_t)b * E_DIM;
    const float* rhrow = rel + (size_t)id * (2 * E_DIM);
    const float* rtrow = rhrow + E_DIM;
    const float4 h4  = ((const float4*)hrow)[lane];
    const float4 rh4 = ((const float4*)rhrow)[lane];
    const float s1 = wave_sum(h4.x * h4.x + h4.y * h4.y + h4.z * h4.z + h4.w * h4.w);
    const float inv = 1.0f / fmaxf(sqrtf(s1), 1e-12f);
    const float p0 = h4.x * inv * rh4.x, p1 = h4.y * inv * rh4.y;
    const float p2 = h4.z * inv * rh4.z, p3 = h4.w * inv * rh4.w;
    const float s2 = wave_sum(p0 * p0 + p1 * p1 + p2 * p2 + p3 * p3);
    if (lane == 0) cvec[b] = s2;

    const float4 rt0 = *(const float4*)(rtrow + e0);
    const float4 rt1 = *(const float4*)(rtrow + e0 + 4);
    const float rt[8] = {rt0.x, rt0.y, rt0.z, rt0.w, rt1.x, rt1.y, rt1.z, rt1.w};
    float v[8];
    if (sqr) {
#pragma unroll
        for (int j = 0; j < 8; ++j) v[j] = rt[j] * rt[j];
    } else {
        const float4 h0 = *(const float4*)(hrow + e0);
        const float4 h1 = *(const float4*)(hrow + e0 + 4);
        const float4 r0 = *(const float4*)(rhrow + e0);
        const float4 r1 = *(const float4*)(rhrow + e0 + 4);
        const float hh[8] = {h0.x, h0.y, h0.z, h0.w, h1.x, h1.y, h1.z, h1.w};
        const float rr[8] = {r0.x, r0.y, r0.z, r0.w, r1.x, r1.y, r1.z, r1.w};
#pragma unroll
        for (int j = 0; j < 8; ++j) v[j] = -2.0f * rt[j] * (hh[j] * inv * rr[j]);
    }
    ushort u[8];
#pragma unroll
    for (int j = 0; j < 8; ++j) u[j] = f2bf(v[j]);
    const int g = b >> 4, m = b & 15;
    *(uint4*)(Abig + (size_t)((g * 16 + s_) * 64 + q * 16 + m) * 8) = *(const uint4*)u;
}

// ---------------- score body (identical to R4) ----------------
// wave wv of block (p_n, b_super): A-group gA = b_super*2 + (wv&1);
// T-groups gT0 = p_n*4 + (wv>>1)*2, +1. A stream shared by waves {wv,wv^2},
// T stream by {wv,wv^1} -> L1 dedup. gridDim.x=32 divisible by 8 -> all 16
// blocks with equal p_n (sharing T) land on one XCD (perf-only heuristic).
__device__ __forceinline__ void score_tile(const ushort* __restrict__ Tbig,
        const ushort* __restrict__ Abig, const float* __restrict__ cvec,
        float* __restrict__ out, int p_n, int b_super, int wv, int lane) {
    const int gA  = b_super * 2 + (wv & 1);
    const int gT0 = p_n * 4 + (wv >> 1) * 2;

    const ushort* Ab  = Abig + (size_t)gA * NSTEP * FRAG_US + lane * 8;
    const ushort* Tb0 = Tbig + (size_t)gT0 * NSTEP * FRAG_US + lane * 8;
    const ushort* Tb1 = Tb0 + (size_t)NSTEP * FRAG_US;

    f32x4 acc0 = {0.f, 0.f, 0.f, 0.f}, acc1 = {0.f, 0.f, 0.f, 0.f};

    bf16x8 a_c  = *(const bf16x8*)(Ab);
    bf16x8 b0_c = *(const bf16x8*)(Tb0);
    bf16x8 b1_c = *(const bf16x8*)(Tb1);
#pragma unroll
    for (int s = 0; s < NSTEP - 1; ++s) {
        const bf16x8 a_n  = *(const bf16x8*)(Ab  + (s + 1) * FRAG_US);
        const bf16x8 b0_n = *(const bf16x8*)(Tb0 + (s + 1) * FRAG_US);
        const bf16x8 b1_n = *(const bf16x8*)(Tb1 + (s + 1) * FRAG_US);
        acc0 = __builtin_amdgcn_mfma_f32_16x16x32_bf16(a_c, b0_c, acc0, 0, 0, 0);
        acc1 = __builtin_amdgcn_mfma_f32_16x16x32_bf16(a_c, b1_c, acc1, 0, 0, 0);
        a_c = a_n; b0_c = b0_n; b1_c = b1_n;
    }
    acc0 = __builtin_amdgcn_mfma_f32_16x16x32_bf16(a_c, b0_c, acc0, 0, 0, 0);
    acc1 = __builtin_amdgcn_mfma_f32_16x16x32_bf16(a_c, b1_c, acc1, 0, 0, 0);

    const int ml = lane & 15, qq = lane >> 4;
    const int b0 = gA * 16;
    const int n0 = gT0 * 16;
#pragma unroll
    for (int r = 0; r < 4; ++r) {
        const int b = b0 + qq * 4 + r;
        const float cb = cvec[b];
        out[(size_t)b * N_DIM + n0 + ml]      = -sqrtf(fmaxf(acc0[r] + cb, 0.f));
        out[(size_t)b * N_DIM + n0 + 16 + ml] = -sqrtf(fmaxf(acc1[r] + cb, 0.f));
    }
}

// ---------------- R6: single cooperative dispatch ----------------
__global__ __launch_bounds__(256) void coop_kernel(
        const float* __restrict__ head, const float* __restrict__ tail,
        const float* __restrict__ rel,  const int* __restrict__ rid,
        ushort* __restrict__ Tbig, ushort* __restrict__ Abig,
        float* __restrict__ cvec, float* __restrict__ out) {
    const int tid = threadIdx.x, lane = tid & 63, wv = tid >> 6;
    const int bx = blockIdx.x, by = blockIdx.y;      // (32, 16) grid
    const int gw = ((by * 32 + bx) << 2) + wv;       // 0..2047, one wave = one row

    // phase 1: dedup'd prep, max parallelism (1-2 rows per wave)
    prep_T_row(tail, Tbig, gw, lane);
    if (gw < B_DIM) prep_A_row(head, rel, rid, Abig, cvec, gw, lane);

    // agent-scope release (L2 writeback), grid barrier, agent-scope acquire
    // (L1/L2 invalidate) -> cross-XCD visibility without any placement
    // assumption.
    __threadfence();
    cg::this_grid().sync();
    __threadfence();

    // phase 2: MFMA score
    score_tile(Tbig, Abig, cvec, out, bx, by, wv, lane);
}

// ---------------- fallback A: R4 two-dispatch path ----------------
__global__ __launch_bounds__(256) void prep_kernel(
        const float* __restrict__ head, const float* __restrict__ tail,
        const float* __restrict__ rel,  const int* __restrict__ rid,
        ushort* __restrict__ Tbig, ushort* __restrict__ Abig,
        float* __restrict__ cvec) {
    const int tid = threadIdx.x, lane = tid & 63, wv = tid >> 6;
    const int w = blockIdx.x * 4 + wv;     // 0..2559
    if (w < N_DIM) prep_T_row(tail, Tbig, w, lane);
    else           prep_A_row(head, rel, rid, Abig, cvec, w - N_DIM, lane);
}

__global__ __launch_bounds__(256) void score_kernel(
        const ushort* __restrict__ Tbig, const ushort* __restrict__ Abig,
        const float* __restrict__ cvec, float* __restrict__ out) {
    const int tid = threadIdx.x, lane = tid & 63, wv = tid >> 6;
    score_tile(Tbig, Abig, cvec, out, blockIdx.x, blockIdx.y, wv, lane);
}

// ---------------- fallback B (no workspace): pure fp32 ----------------
__device__ inline float block_reduce_sum_256(float v, float* buf) {
#pragma unroll
    for (int o = 32; o > 0; o >>= 1) v += __shfl_down(v, o, 64);
    const int lane = threadIdx.x & 63, wid = threadIdx.x >> 6;
    __syncthreads();
    if (lane == 0) buf[wid] = v;
    __syncthreads();
    return buf[0] + buf[1] + buf[2] + buf[3];
}

__global__ __launch_bounds__(256) void fallback_kernel(
        const float* __restrict__ head, const float* __restrict__ tail,
        const float* __restrict__ rel,  const int* __restrict__ rid,
        float* __restrict__ out) {
    __shared__ float Hh[E_DIM];
    __shared__ float RT[E_DIM];
    __shared__ float buf[4];
    const int b = blockIdx.x;
    const int tid = threadIdx.x;
    const float hv = head[(size_t)b * E_DIM + tid];
    const int id = rid[b];
    const float rh = rel[(size_t)id * (2 * E_DIM) + tid];
    const float rt = rel[(size_t)id * (2 * E_DIM) + E_DIM + tid];
    const float tot = block_reduce_sum_256(hv * hv, buf);
    const float inv = 1.0f / fmaxf(sqrtf(tot), 1e-12f);
    const float HhV = hv * inv * rh;
    Hh[tid] = HhV; RT[tid] = rt;
    const float c = block_reduce_sum_256(HhV * HhV, buf);
    __syncthreads();
    for (int n = tid; n < N_DIM; n += 256) {
        float S1 = 0.f, S2 = 0.f, Stt = 0.f;
        for (int e = 0; e < E_DIM; ++e) {
            const float tv = tail[(size_t)n * E_DIM + e];
            const float p = tv * RT[e];
            S1 += p * p; S2 += p * Hh[e]; Stt += tv * tv;
        }
        const float al = 1.0f / fmaxf(sqrtf(Stt), 1e-12f);
        const float x = al * al * S1 - 2.0f * al * S2 + c;
        out[(size_t)b * N_DIM + n] = -sqrtf(fmaxf(x, 0.f));
    }
}

extern "C" void kernel_launch(void* const* d_in, const int* in_sizes, int n_in,
                              void* d_out, int out_size, void* d_ws, size_t ws_size,
                              hipStream_t stream) {
    const float* head = (const float*)d_in[0];
    const float* tail = (const float*)d_in[1];
    const float* rel  = (const float*)d_in[2];
    const int*   rid  = (const int*)d_in[3];
    float* out = (float*)d_out;

    const size_t needT = (size_t)N_DIM * K_DIM * sizeof(ushort);   // 2 MB
    const size_t needA = (size_t)B_DIM * K_DIM * sizeof(ushort);   // 512 KB
    const size_t needC = (size_t)B_DIM * sizeof(float);            // 2 KB
    if (ws_size >= needT + needA + needC) {
        ushort* Tbig = (ushort*)d_ws;
        ushort* Abig = Tbig + (size_t)N_DIM * K_DIM;
        float*  cvec = (float*)(Abig + (size_t)B_DIM * K_DIM);
        dim3 grid(N_DIM / 64, B_DIM / 32);   // (32, 16) = 512 blocks, 256 thr
        void* args[] = {(void*)&head, (void*)&tail, (void*)&rel, (void*)&rid,
                        (void*)&Tbig, (void*)&Abig, (void*)&cvec, (void*)&out};
        hipError_t e = hipLaunchCooperativeKernel(
                reinterpret_cast<const void*>(coop_kernel), grid, dim3(256),
                args, 0, stream);
        if (e != hipSuccess) {
            // fallback: R4 two-dispatch path (known-good, 68 us)
            prep_kernel<<<(N_DIM + B_DIM) / 4, 256, 0, stream>>>(
                    head, tail, rel, rid, Tbig, Abig, cvec);
            score_kernel<<<grid, 256, 0, stream>>>(Tbig, Abig, cvec, out);
        }
    } else {
        fallback_kernel<<<B_DIM, 256, 0, stream>>>(head, tail, rel, rid, out);
    }
}

// Round 3
// 68.116 us; speedup vs baseline: 3.2269x; 3.2269x over previous
//
#include <hip/hip_runtime.h>
#include <hip/hip_bf16.h>

// PairRE scoring: out[b,n] = -|| t_hat[n]*rt[b] - h_hat[b]*rh[b] ||_2
// B=512, N=2048, E=256.
//
// x(b,n) = dot([T^2 | T]_n , [rt^2 | -2*rt*Hh]_b) + c_b,
//   T = t/||t||, Hh = (h/||h||)*rh, c_b = ||Hh_b||^2.
//
// R7: back to the verified R4 two-dispatch structure (68 us).
// Post-mortems: R5 (LDS fusion) lost to 25x redundant prep VALU (41 us
// kernel); R6 (cooperative grid sync) lost to a ~130 us cg::sync barrier
// (VALUBusy 0.96%). Cost model across R4/R5/R6: dur = 41 us unconditional
// workspace-poison fill + ~10 us fixed overhead + kernel time; R4's
// prep+score = 15-17 us vs ~6 us roofline -> slack is L3 load latency in
// score at 2 waves/SIMD with only a 1-deep prefetch.
// Change vs R4: score gets a 4-deep explicit prefetch pipeline (12 loads
// in flight per wave, compile-time-indexed stages -> registers, ~+48 VGPR,
// occupancy unchanged at 2 blocks/CU). Prep numerics bit-identical.

#define B_DIM 512
#define N_DIM 2048
#define E_DIM 256
#define K_DIM 512
#define NSTEP 16        // K/32 MFMA k-steps
#define FRAG_US 512     // ushorts per packed fragment (64 lanes * 8)
#define PF 4            // prefetch depth (must divide NSTEP)

typedef __attribute__((ext_vector_type(8))) __bf16 bf16x8;
typedef __attribute__((ext_vector_type(4))) float f32x4;

__device__ inline ushort f2bf(float x) {
    __hip_bfloat16 h = __float2bfloat16(x);   // RNE
    union { __hip_bfloat16 b; ushort u; } cv_; cv_.b = h; return cv_.u;
}

__device__ inline float wave_sum(float v) {
#pragma unroll
    for (int m = 1; m < 64; m <<= 1) v += __shfl_xor(v, m, 64);
    return v;
}

// ---------------- prep bodies (identical numerics to R4) ----------------
// Packed addr for row r=g*16+m, k=c*8+j (c=s*4+q): dst=((g*16+s)*64+q*16+m)*8
// Lane writes k0=lane*8 .. +7  ->  s=lane>>2, q=lane&3.
__device__ __forceinline__ void prep_T_row(const float* __restrict__ tail,
        ushort* __restrict__ Tbig, int n, int lane) {
    const int s_ = lane >> 2, q = lane & 3;
    const int k0 = lane * 8;
    const bool sqr = (k0 < E_DIM);
    const int e0 = k0 & (E_DIM - 1);
    const float* row = tail + (size_t)n * E_DIM;
    const float4 v4 = ((const float4*)row)[lane];
    const float s = wave_sum(v4.x * v4.x + v4.y * v4.y + v4.z * v4.z + v4.w * v4.w);
    const float inv = 1.0f / fmaxf(sqrtf(s), 1e-12f);
    const float4 f0 = *(const float4*)(row + e0);
    const float4 f1 = *(const float4*)(row + e0 + 4);
    const float v[8] = {f0.x, f0.y, f0.z, f0.w, f1.x, f1.y, f1.z, f1.w};
    ushort u[8];
#pragma unroll
    for (int j = 0; j < 8; ++j) {
        float x = v[j] * inv;
        if (sqr) x *= x;
        u[j] = f2bf(x);
    }
    const int g = n >> 4, m = n & 15;
    *(uint4*)(Tbig + (size_t)((g * 16 + s_) * 64 + q * 16 + m) * 8) = *(const uint4*)u;
}

__device__ __forceinline__ void prep_A_row(const float* __restrict__ head,
        const float* __restrict__ rel, const int* __restrict__ rid,
        ushort* __restrict__ Abig, float* __restrict__ cvec, int b, int lane) {
    const int s_ = lane >> 2, q = lane & 3;
    const int k0 = lane * 8;
    const bool sqr = (k0 < E_DIM);
    const int e0 = k0 & (E_DIM - 1);
    const int id = rid[b];
    const float* hrow  = head + (size_t)b * E_DIM;
    const float* rhrow = rel + (size_t)id * (2 * E_DIM);
    const float* rtrow = rhrow + E_DIM;
    const float4 h4  = ((const float4*)hrow)[lane];
    const float4 rh4 = ((const float4*)rhrow)[lane];
    const float s1 = wave_sum(h4.x * h4.x + h4.y * h4.y + h4.z * h4.z + h4.w * h4.w);
    const float inv = 1.0f / fmaxf(sqrtf(s1), 1e-12f);
    const float p0 = h4.x * inv * rh4.x, p1 = h4.y * inv * rh4.y;
    const float p2 = h4.z * inv * rh4.z, p3 = h4.w * inv * rh4.w;
    const float s2 = wave_sum(p0 * p0 + p1 * p1 + p2 * p2 + p3 * p3);
    if (lane == 0) cvec[b] = s2;

    const float4 rt0 = *(const float4*)(rtrow + e0);
    const float4 rt1 = *(const float4*)(rtrow + e0 + 4);
    const float rt[8] = {rt0.x, rt0.y, rt0.z, rt0.w, rt1.x, rt1.y, rt1.z, rt1.w};
    float v[8];
    if (sqr) {
#pragma unroll
        for (int j = 0; j < 8; ++j) v[j] = rt[j] * rt[j];
    } else {
        const float4 h0 = *(const float4*)(hrow + e0);
        const float4 h1 = *(const float4*)(hrow + e0 + 4);
        const float4 r0 = *(const float4*)(rhrow + e0);
        const float4 r1 = *(const float4*)(rhrow + e0 + 4);
        const float hh[8] = {h0.x, h0.y, h0.z, h0.w, h1.x, h1.y, h1.z, h1.w};
        const float rr[8] = {r0.x, r0.y, r0.z, r0.w, r1.x, r1.y, r1.z, r1.w};
#pragma unroll
        for (int j = 0; j < 8; ++j) v[j] = -2.0f * rt[j] * (hh[j] * inv * rr[j]);
    }
    ushort u[8];
#pragma unroll
    for (int j = 0; j < 8; ++j) u[j] = f2bf(v[j]);
    const int g = b >> 4, m = b & 15;
    *(uint4*)(Abig + (size_t)((g * 16 + s_) * 64 + q * 16 + m) * 8) = *(const uint4*)u;
}

__global__ __launch_bounds__(256) void prep_kernel(
        const float* __restrict__ head, const float* __restrict__ tail,
        const float* __restrict__ rel,  const int* __restrict__ rid,
        ushort* __restrict__ Tbig, ushort* __restrict__ Abig,
        float* __restrict__ cvec) {
    const int tid = threadIdx.x, lane = tid & 63, wv = tid >> 6;
    const int w = blockIdx.x * 4 + wv;     // 0..2559
    if (w < N_DIM) prep_T_row(tail, Tbig, w, lane);
    else           prep_A_row(head, rel, rid, Abig, cvec, w - N_DIM, lane);
}

// ---------------- score: no LDS/barriers; 2x2 wave grid; 4-deep prefetch --
// grid = (32, 16): blockIdx.x = p_n (64 n-cols), blockIdx.y = b_super (32
// b-rows). wave wv: A-group gA = b_super*2 + (wv&1); T-groups gT0 =
// p_n*4 + (wv>>1)*2, +1. A stream shared by waves {wv, wv^2}, T stream by
// {wv, wv^1} -> L1 dedup. gridDim.x=32 divisible by 8 -> all 16 blocks with
// equal p_n (sharing T) land on one XCD (perf heuristic only).
// PF=4 stages x 3 streams = 12 loads in flight per wave (vs 3 in R4):
// at 2 waves/SIMD this is 24 outstanding L3 reads per SIMD, hiding the
// ~500cy post-flush fragment latency. All stage indices compile-time
// (full unroll) so stages live in VGPRs, not scratch.
__global__ __launch_bounds__(256) void score_kernel(
        const ushort* __restrict__ Tbig, const ushort* __restrict__ Abig,
        const float* __restrict__ cvec, float* __restrict__ out) {
    const int tid = threadIdx.x, lane = tid & 63, wv = tid >> 6;
    const int p_n = blockIdx.x, b_super = blockIdx.y;
    const int gA  = b_super * 2 + (wv & 1);
    const int gT0 = p_n * 4 + (wv >> 1) * 2;

    const ushort* Ab  = Abig + (size_t)gA * NSTEP * FRAG_US + lane * 8;
    const ushort* Tb0 = Tbig + (size_t)gT0 * NSTEP * FRAG_US + lane * 8;
    const ushort* Tb1 = Tb0 + (size_t)NSTEP * FRAG_US;

    bf16x8 a_s[PF], b0_s[PF], b1_s[PF];
#pragma unroll
    for (int i = 0; i < PF; ++i) {
        a_s[i]  = *(const bf16x8*)(Ab  + i * FRAG_US);
        b0_s[i] = *(const bf16x8*)(Tb0 + i * FRAG_US);
        b1_s[i] = *(const bf16x8*)(Tb1 + i * FRAG_US);
    }

    f32x4 acc0 = {0.f, 0.f, 0.f, 0.f}, acc1 = {0.f, 0.f, 0.f, 0.f};
#pragma unroll
    for (int s = 0; s < NSTEP; ++s) {
        const int sl = s & (PF - 1);          // compile-time after unroll
        const bf16x8 ca  = a_s[sl];
        const bf16x8 cb0 = b0_s[sl];
        const bf16x8 cb1 = b1_s[sl];
        if (s + PF < NSTEP) {
            a_s[sl]  = *(const bf16x8*)(Ab  + (s + PF) * FRAG_US);
            b0_s[sl] = *(const bf16x8*)(Tb0 + (s + PF) * FRAG_US);
            b1_s[sl] = *(const bf16x8*)(Tb1 + (s + PF) * FRAG_US);
        }
        acc0 = __builtin_amdgcn_mfma_f32_16x16x32_bf16(ca, cb0, acc0, 0, 0, 0);
        acc1 = __builtin_amdgcn_mfma_f32_16x16x32_bf16(ca, cb1, acc1, 0, 0, 0);
    }

    // Epilogue: C layout col=lane&15 (n), row=(lane>>4)*4+r (b).
    const int ml = lane & 15, qq = lane >> 4;
    const int b0 = gA * 16;
    const int n0 = gT0 * 16;
#pragma unroll
    for (int r = 0; r < 4; ++r) {
        const int b = b0 + qq * 4 + r;
        const float cb = cvec[b];
        out[(size_t)b * N_DIM + n0 + ml]      = -sqrtf(fmaxf(acc0[r] + cb, 0.f));
        out[(size_t)b * N_DIM + n0 + 16 + ml] = -sqrtf(fmaxf(acc1[r] + cb, 0.f));
    }
}

// ---------------- fallback (no workspace): pure fp32 ----------------
__device__ inline float block_reduce_sum_256(float v, float* buf) {
#pragma unroll
    for (int o = 32; o > 0; o >>= 1) v += __shfl_down(v, o, 64);
    const int lane = threadIdx.x & 63, wid = threadIdx.x >> 6;
    __syncthreads();
    if (lane == 0) buf[wid] = v;
    __syncthreads();
    return buf[0] + buf[1] + buf[2] + buf[3];
}

__global__ __launch_bounds__(256) void fallback_kernel(
        const float* __restrict__ head, const float* __restrict__ tail,
        const float* __restrict__ rel,  const int* __restrict__ rid,
        float* __restrict__ out) {
    __shared__ float Hh[E_DIM];
    __shared__ float RT[E_DIM];
    __shared__ float buf[4];
    const int b = blockIdx.x;
    const int tid = threadIdx.x;
    const float hv = head[(size_t)b * E_DIM + tid];
    const int id = rid[b];
    const float rh = rel[(size_t)id * (2 * E_DIM) + tid];
    const float rt = rel[(size_t)id * (2 * E_DIM) + E_DIM + tid];
    const float tot = block_reduce_sum_256(hv * hv, buf);
    const float inv = 1.0f / fmaxf(sqrtf(tot), 1e-12f);
    const float HhV = hv * inv * rh;
    Hh[tid] = HhV; RT[tid] = rt;
    const float c = block_reduce_sum_256(HhV * HhV, buf);
    __syncthreads();
    for (int n = tid; n < N_DIM; n += 256) {
        float S1 = 0.f, S2 = 0.f, Stt = 0.f;
        for (int e = 0; e < E_DIM; ++e) {
            const float tv = tail[(size_t)n * E_DIM + e];
            const float p = tv * RT[e];
            S1 += p * p; S2 += p * Hh[e]; Stt += tv * tv;
        }
        const float al = 1.0f / fmaxf(sqrtf(Stt), 1e-12f);
        const float x = al * al * S1 - 2.0f * al * S2 + c;
        out[(size_t)b * N_DIM + n] = -sqrtf(fmaxf(x, 0.f));
    }
}

extern "C" void kernel_launch(void* const* d_in, const int* in_sizes, int n_in,
                              void* d_out, int out_size, void* d_ws, size_t ws_size,
                              hipStream_t stream) {
    const float* head = (const float*)d_in[0];
    const float* tail = (const float*)d_in[1];
    const float* rel  = (const float*)d_in[2];
    const int*   rid  = (const int*)d_in[3];
    float* out = (float*)d_out;

    const size_t needT = (size_t)N_DIM * K_DIM * sizeof(ushort);   // 2 MB
    const size_t needA = (size_t)B_DIM * K_DIM * sizeof(ushort);   // 512 KB
    const size_t needC = (size_t)B_DIM * sizeof(float);            // 2 KB
    if (ws_size >= needT + needA + needC) {
        ushort* Tbig = (ushort*)d_ws;
        ushort* Abig = Tbig + (size_t)N_DIM * K_DIM;
        float*  cvec = (float*)(Abig + (size_t)B_DIM * K_DIM);
        prep_kernel<<<(N_DIM + B_DIM) / 4, 256, 0, stream>>>(head, tail, rel, rid,
                                                             Tbig, Abig, cvec);
        dim3 grid(N_DIM / 64, B_DIM / 32);   // (32, 16) = 512 blocks
        score_kernel<<<grid, 256, 0, stream>>>(Tbig, Abig, cvec, out);
    } else {
        fallback_kernel<<<B_DIM, 256, 0, stream>>>(head, tail, rel, rid, out);
    }
}